// Round 1
// baseline (5308.282 us; speedup 1.0000x reference)
//
#include <hip/hip_runtime.h>
#include <math.h>

#pragma clang fp contract(off)

#define NROWS 131072

// selu matching np: scale * where(x>0, x, alpha*expm1(x)), each op rounded separately
__device__ __forceinline__ float selu_f(float v) {
    float em  = expm1f(v);
    float neg = 1.6732632423543772f * em;
    float r   = v > 0.0f ? v : neg;
    return 1.0507009873554805f * r;
}

__device__ __forceinline__ float4 ldf4(const float* p) { return *(const float4*)p; }

__device__ __forceinline__ void ld2x4(float4* b, const float* p) { b[0] = ldf4(p); b[1] = ldf4(p + 4); }

__device__ __forceinline__ void fma8a(float* a, const float4* w, float h) {
    a[0] = __builtin_fmaf(w[0].x, h, a[0]);  a[1] = __builtin_fmaf(w[0].y, h, a[1]);
    a[2] = __builtin_fmaf(w[0].z, h, a[2]);  a[3] = __builtin_fmaf(w[0].w, h, a[3]);
    a[4] = __builtin_fmaf(w[1].x, h, a[4]);  a[5] = __builtin_fmaf(w[1].y, h, a[5]);
    a[6] = __builtin_fmaf(w[1].z, h, a[6]);  a[7] = __builtin_fmaf(w[1].w, h, a[7]);
}

// rotate step: issue next row's 2xf4 loads, then consume current buffer, then rotate in
__device__ __forceinline__ void step8(float* acc, float4* wb, const float* nextp, float h) {
    float4 t0 = ldf4(nextp), t1 = ldf4(nextp + 4);
    fma8a(acc, wb, h);
    wb[0] = t0; wb[1] = t1;
}

// ---------- prep 1: W2 [256,256] -> W2T [j][c]; W3 [64,256] -> W3T [c][e]; W1 [256,64] -> W1T [j][c]
__global__ void prep_transpose(const float* __restrict__ W1, const float* __restrict__ W2,
                               const float* __restrict__ W3,
                               float* __restrict__ W1T, float* __restrict__ W2T,
                               float* __restrict__ W3T) {
    int id = blockIdx.x * 256 + threadIdx.x;
    if (id < 65536) { int c = id >> 8, j = id & 255; W2T[j * 256 + c] = W2[id]; }
    int id2 = id - 65536;
    if (id2 >= 0 && id2 < 16384) { int e = id2 >> 8, c = id2 & 255; W3T[c * 64 + e] = W3[id2]; }
    int id3 = id - 81920;
    if (id3 >= 0 && id3 < 16384) { int c = id3 >> 6, j = id3 & 63; W1T[j * 256 + c] = W1[id3]; }
}

// ---------- prep 2: decoder table dec_out[k] = decoder(emb[k]), and en[k] = ||emb_k||^2 ----------
__global__ void prep_decoder(const float* __restrict__ emb,
                             const float* __restrict__ Wd1, const float* __restrict__ bd1,
                             const float* __restrict__ Wd2, const float* __restrict__ bd2,
                             const float* __restrict__ Wd3, const float* __restrict__ bd3,
                             float* __restrict__ dec_out, float* __restrict__ en) {
    __shared__ float e[64];
    __shared__ float h1[256];
    __shared__ float h2[256];
    const int t = threadIdx.x; // 256 threads
    for (int kc = 0; kc < 4; ++kc) {
        const int k = blockIdx.x * 4 + kc;
        __syncthreads();
        if (t < 64) e[t] = emb[k * 64 + t];
        __syncthreads();
        {
            float acc = 0.0f;
            const float* w = Wd1 + t * 64;
            #pragma unroll
            for (int j = 0; j < 64; ++j) acc = __builtin_fmaf(w[j], e[j], acc);
            h1[t] = selu_f(acc + bd1[t]);
        }
        __syncthreads();
        {
            float acc = 0.0f;
            const float* w = Wd2 + t * 256;
            #pragma unroll 8
            for (int j = 0; j < 256; ++j) acc = __builtin_fmaf(w[j], h1[j], acc);
            h2[t] = selu_f(acc + bd2[t]);
        }
        __syncthreads();
        if (t < 64) {
            float acc = 0.0f;
            const float* w = Wd3 + t * 256;
            #pragma unroll 8
            for (int j = 0; j < 256; ++j) acc = __builtin_fmaf(w[j], h2[j], acc);
            dec_out[k * 64 + t] = acc + bd3[t];
        }
        if (t == 0) {
            float r[8];
            #pragma unroll
            for (int u = 0; u < 8; ++u) r[u] = e[u] * e[u];
            #pragma unroll
            for (int i = 8; i < 64; i += 8) {
                #pragma unroll
                for (int u = 0; u < 8; ++u) { float p = e[i + u] * e[i + u]; r[u] = r[u] + p; }
            }
            en[k] = ((r[0] + r[1]) + (r[2] + r[3])) + ((r[4] + r[5]) + (r[6] + r[7]));
        }
    }
}

// ---------- main kernel ----------
// block = 512 threads = 8 waves, 64 rows (lane = row). Same 64-row tile / same 80 KB LDS as the
// 256-thread version, but twice the waves per LDS byte: 2 blocks/CU -> 16 waves/CU = 4 waves/SIMD
// (was 2). Each wave owns HALF the old column slice (8 L2-cols/group, 8 e's, 128 codes), so all
// per-accumulator chains keep the exact same order -> bit-identical output.
// VGPR must stay <= 128 for 4 waves/SIMD: waves_per_eu(4) pins the budget (est. peak ~90 live).
__global__ __launch_bounds__(512) __attribute__((amdgpu_waves_per_eu(4)))
void vqvae_main(const float* __restrict__ x,
                const float* __restrict__ b1, const float* __restrict__ b2,
                const float* __restrict__ b3,
                const float* __restrict__ W1T, const float* __restrict__ W2T,
                const float* __restrict__ W3T,
                const float* __restrict__ emb, const float* __restrict__ en,
                const float* __restrict__ dec_out, float* __restrict__ out) {
    __shared__ __align__(16) float R1[16384];
    __shared__ __align__(16) float aux[4096];

    const int t    = threadIdx.x;
    const int wave = t >> 6;      // 0..7
    const int lane = t & 63;
    const size_t rowbase = (size_t)blockIdx.x * 64;

    // opaque zero in a VGPR: keeps uniform loads on the vector pipe (vmcnt, pipelinable)
    int lz;
    asm volatile("v_mov_b32 %0, 0" : "=v"(lz));

    const float* W1Tv = W1T + lz;
    const float* W2Tv = W2T + lz;
    const float* W3Tv = W3T + lz;
    const float* b1v  = b1 + lz;
    const float* b2v  = b2 + lz;
    const float* b3v  = b3 + lz;
    const float* env  = en + lz;
    const float* embv = emb + lz;

    // ---- phase 0: stage x tile transposed into aux: xT[j][r]
    #pragma unroll
    for (int q = 0; q < 2; ++q) {
        int f = t + 512 * q;
        int r = f >> 4, c4 = f & 15;
        float4 v = ldf4(x + (rowbase + r) * 64 + c4 * 4);
        aux[(c4 * 4 + 0) * 64 + r] = v.x;
        aux[(c4 * 4 + 1) * 64 + r] = v.y;
        aux[(c4 * 4 + 2) * 64 + r] = v.z;
        aux[(c4 * 4 + 3) * 64 + r] = v.w;
    }
    __syncthreads();

    // ---- phase 1: layer1. group g: this wave computes cols cg=64g+8*wave .. +8.
    // h1 stored as j-pairs: R1[(c>>1)*128 + lane*2 + (c&1)]
    for (int g = 0; g < 4; ++g) {
        const int cg = g * 64 + wave * 8;
        const float* wp = W1Tv + cg;      // row j at wp + j*256
        float4 A0[2], A1[2], A2[2], A3[2];
        ld2x4(A0, wp); ld2x4(A1, wp + 256); ld2x4(A2, wp + 512); ld2x4(A3, wp + 768);
        float acc[8];
        #pragma unroll
        for (int u = 0; u < 8; ++u) acc[u] = 0.0f;
        #pragma unroll 1
        for (int j = 0; j < 64; j += 4) {
            const float* np = wp + (j + 4) * 256;   // rows 64..67 overrun into W3T region (in-ws, unused)
            step8(acc, A0, np,        aux[(j + 0) * 64 + lane]);
            step8(acc, A1, np + 256,  aux[(j + 1) * 64 + lane]);
            step8(acc, A2, np + 512,  aux[(j + 2) * 64 + lane]);
            step8(acc, A3, np + 768,  aux[(j + 3) * 64 + lane]);
        }
        float bb[8];
        *(float4*)&bb[0] = ldf4(b1v + cg);
        *(float4*)&bb[4] = ldf4(b1v + cg + 4);
        float hv[8];
        #pragma unroll
        for (int u = 0; u < 8; ++u) hv[u] = selu_f(acc[u] + bb[u]);
        #pragma unroll
        for (int up = 0; up < 4; ++up) {
            *(float2*)&R1[((cg >> 1) + up) * 128 + (lane << 1)] = make_float2(hv[2 * up], hv[2 * up + 1]);
        }
    }
    __syncthreads();

    // ---- phase 2: layer2 + layer3, group-staged.
    // group g = col-block [64g, 64g+64): wave computes 8 cols (cg=64g+8*wave), stages h2 in aux,
    // then folds the whole 64-col block into its e-range er=[8*wave, +8) -> partial P_g.
    // z = ((P0+P1)+(P2+P3)) + b3  (identical chain to the passing rounds)
    const int er = wave * 8;
    float s01[8], s23[8];
    for (int g = 0; g < 4; ++g) {
        const int cg = g * 64 + wave * 8;
        const float* wp = W2Tv + cg;      // row j at wp + j*256
        float4 A0[2], A1[2], A2[2], A3[2];
        ld2x4(A0, wp); ld2x4(A1, wp + 256); ld2x4(A2, wp + 512); ld2x4(A3, wp + 768);
        float acc[8];
        #pragma unroll
        for (int u = 0; u < 8; ++u) acc[u] = 0.0f;
        #pragma unroll 1
        for (int j = 0; j < 256; j += 4) {
            const float* np = wp + (j + 4) * 256; // rows 256..259 land in W1T region (in-ws, unused)
            float2 h01 = *(const float2*)&R1[(j >> 1) * 128 + (lane << 1)];
            step8(acc, A0, np,        h01.x);
            step8(acc, A1, np + 256,  h01.y);
            float2 h23 = *(const float2*)&R1[((j >> 1) + 1) * 128 + (lane << 1)];
            step8(acc, A2, np + 512,  h23.x);
            step8(acc, A3, np + 768,  h23.y);
        }
        __syncthreads();   // previous fold's readers of aux are done
        {
            float bb[8];
            *(float4*)&bb[0] = ldf4(b2v + cg);
            *(float4*)&bb[4] = ldf4(b2v + cg + 4);
            #pragma unroll
            for (int u = 0; u < 8; ++u)
                aux[(wave * 8 + u) * 64 + lane] = selu_f(acc[u] + bb[u]);
        }
        __syncthreads();   // h2 of this col-block visible
        // fold col-block g (cols 64g..64g+63 ascending) into e-range er..er+8
        const float* w3p = W3Tv + g * 4096 + er;    // col (64g+c) at w3p + c*64
        float4 F0[2], F1[2], F2[2], F3[2];
        ld2x4(F0, w3p); ld2x4(F1, w3p + 64); ld2x4(F2, w3p + 128); ld2x4(F3, w3p + 192);
        float P[8];
        #pragma unroll
        for (int u = 0; u < 8; ++u) P[u] = 0.0f;
        #pragma unroll 1
        for (int c = 0; c < 64; c += 4) {
            const float* np = w3p + (c + 4) * 64;  // col 64..67 overrun into en pad (in-ws)
            step8(P, F0, np,        aux[(c + 0) * 64 + lane]);
            step8(P, F1, np + 64,   aux[(c + 1) * 64 + lane]);
            step8(P, F2, np + 128,  aux[(c + 2) * 64 + lane]);
            step8(P, F3, np + 192,  aux[(c + 3) * 64 + lane]);
        }
        if (g == 0) {
            #pragma unroll
            for (int u = 0; u < 8; ++u) s01[u] = P[u];
        } else if (g == 1) {
            #pragma unroll
            for (int u = 0; u < 8; ++u) s01[u] = s01[u] + P[u];
        } else if (g == 2) {
            #pragma unroll
            for (int u = 0; u < 8; ++u) s23[u] = P[u];
        } else {
            #pragma unroll
            for (int u = 0; u < 8; ++u) s23[u] = s23[u] + P[u];
        }
    }

    // ---- phase 3: z = (s01+s23)+b3; park z in LDS (zs[lane][e], stride 68 -> 2-way free b128)
    {
        float bb[8];
        *(float4*)&bb[0] = ldf4(b3v + er);
        *(float4*)&bb[4] = ldf4(b3v + er + 4);
        float zv[8];
        #pragma unroll
        for (int u = 0; u < 8; ++u) zv[u] = (s01[u] + s23[u]) + bb[u];
        *(float4*)&R1[lane * 68 + er]     = make_float4(zv[0], zv[1], zv[2], zv[3]);
        *(float4*)&R1[lane * 68 + er + 4] = make_float4(zv[4], zv[5], zv[6], zv[7]);
    }
    __syncthreads();

    // A = ||z||^2 with numpy pairwise chain (8 strided accumulators, balanced tree)
    float A;
    {
        float z[64];
        #pragma unroll
        for (int m = 0; m < 16; ++m) {
            float4 v = *(const float4*)&R1[lane * 68 + m * 4];
            z[4 * m] = v.x; z[4 * m + 1] = v.y; z[4 * m + 2] = v.z; z[4 * m + 3] = v.w;
        }
        float r[8];
        #pragma unroll
        for (int u = 0; u < 8; ++u) r[u] = z[u] * z[u];
        #pragma unroll
        for (int i = 8; i < 64; i += 8) {
            #pragma unroll
            for (int u = 0; u < 8; ++u) { float p = z[i + u] * z[i + u]; r[u] = r[u] + p; }
        }
        A = ((r[0] + r[1]) + (r[2] + r[3])) + ((r[4] + r[5]) + (r[6] + r[7]));
    }

    // ---- phase 4: scores over wave's 128-code slice, 8-code chunks, z quarters re-read from LDS
    float best = 3.4e38f;
    const int k0 = wave * 128;
    int bk = k0;
    const float* embw = embv + (size_t)k0 * 64;
    #pragma unroll 1
    for (int kc = 0; kc < 128; kc += 8) {
        float4 en03 = ldf4(env + k0 + kc);
        float4 en47 = ldf4(env + k0 + kc + 4);
        float d0[8], d1[8], d2[8], d3[8];
        #pragma unroll
        for (int c = 0; c < 8; ++c) { d0[c] = 0.f; d1[c] = 0.f; d2[c] = 0.f; d3[c] = 0.f; }
        #pragma unroll
        for (int q = 0; q < 4; ++q) {
            float4 zq0 = *(const float4*)&R1[lane * 68 + q * 16];
            float4 zq1 = *(const float4*)&R1[lane * 68 + q * 16 + 4];
            float4 zq2 = *(const float4*)&R1[lane * 68 + q * 16 + 8];
            float4 zq3 = *(const float4*)&R1[lane * 68 + q * 16 + 12];
            #pragma unroll
            for (int c = 0; c < 8; ++c) {
                const float* ep = embw + (kc + c) * 64 + q * 16;
                float4 e0 = ldf4(ep), e1 = ldf4(ep + 4), e2 = ldf4(ep + 8), e3 = ldf4(ep + 12);
                d0[c] = __builtin_fmaf(zq0.x, e0.x, d0[c]);
                d1[c] = __builtin_fmaf(zq0.y, e0.y, d1[c]);
                d2[c] = __builtin_fmaf(zq0.z, e0.z, d2[c]);
                d3[c] = __builtin_fmaf(zq0.w, e0.w, d3[c]);
                d0[c] = __builtin_fmaf(zq1.x, e1.x, d0[c]);
                d1[c] = __builtin_fmaf(zq1.y, e1.y, d1[c]);
                d2[c] = __builtin_fmaf(zq1.z, e1.z, d2[c]);
                d3[c] = __builtin_fmaf(zq1.w, e1.w, d3[c]);
                d0[c] = __builtin_fmaf(zq2.x, e2.x, d0[c]);
                d1[c] = __builtin_fmaf(zq2.y, e2.y, d1[c]);
                d2[c] = __builtin_fmaf(zq2.z, e2.z, d2[c]);
                d3[c] = __builtin_fmaf(zq2.w, e2.w, d3[c]);
                d0[c] = __builtin_fmaf(zq3.x, e3.x, d0[c]);
                d1[c] = __builtin_fmaf(zq3.y, e3.y, d1[c]);
                d2[c] = __builtin_fmaf(zq3.z, e3.z, d2[c]);
                d3[c] = __builtin_fmaf(zq3.w, e3.w, d3[c]);
            }
        }
        float enb[8];
        *(float4*)&enb[0] = en03; *(float4*)&enb[4] = en47;
        #pragma unroll
        for (int c = 0; c < 8; ++c) {
            float dot = (d0[c] + d1[c]) + (d2[c] + d3[c]);
            float tt  = __builtin_fmaf(-2.0f, dot, A);
            float s   = tt + enb[c];
            if (s < best) { best = s; bk = k0 + kc + c; }
        }
    }

    // ---- phase 5: cross-wave argmin (ascending wave => first-min); aux now dead -> cand storage
    float* cand_s = aux + 64;             // 512 floats
    int*   cand_k = ((int*)aux) + 576;    // 512 ints
    int*   ixp    = (int*)aux;            // 64 ints
    cand_s[wave * 64 + lane] = best;
    cand_k[wave * 64 + lane] = bk;
    __syncthreads();
    if (t < 64) {
        float s0 = cand_s[t];
        int   kk = cand_k[t];
        #pragma unroll
        for (int w2 = 1; w2 < 8; ++w2) {
            float sw = cand_s[w2 * 64 + t];
            if (sw < s0) { s0 = sw; kk = cand_k[w2 * 64 + t]; }
        }
        ixp[t] = kk;
        out[(size_t)NROWS * 64 + rowbase + t] = (float)kk;
    }
    __syncthreads();

    // ---- phase 6: recon = dec_out[idx], coalesced f4 store
    #pragma unroll
    for (int q = 0; q < 2; ++q) {
        int f = t + 512 * q;
        int r = f >> 4, c4 = f & 15;
        float4 v = ldf4(dec_out + (size_t)ixp[r] * 64 + c4 * 4);
        *(float4*)(out + (rowbase + r) * 64 + c4 * 4) = v;
    }
}

extern "C" void kernel_launch(void* const* d_in, const int* in_sizes, int n_in,
                              void* d_out, int out_size, void* d_ws, size_t ws_size,
                              hipStream_t stream) {
    const float* x   = (const float*)d_in[0];
    const float* We1 = (const float*)d_in[1];
    const float* be1 = (const float*)d_in[2];
    const float* We2 = (const float*)d_in[3];
    const float* be2 = (const float*)d_in[4];
    const float* We3 = (const float*)d_in[5];
    const float* be3 = (const float*)d_in[6];
    const float* emb = (const float*)d_in[7];
    const float* Wd1 = (const float*)d_in[8];
    const float* bd1 = (const float*)d_in[9];
    const float* Wd2 = (const float*)d_in[10];
    const float* bd2 = (const float*)d_in[11];
    const float* Wd3 = (const float*)d_in[12];
    const float* bd3 = (const float*)d_in[13];
    float* out = (float*)d_out;

    // ws layout (floats): dec_out[65536] | W2T[65536] | W1T[16384] | W3T[16384] | en[1024+pad]
    float* ws      = (float*)d_ws;
    float* dec_out = ws;
    float* W2T     = ws + 65536;
    float* W1T     = ws + 131072;
    float* W3T     = ws + 147456;
    float* en      = ws + 163840;   // en + 1 KB pad absorbs fold prefetch overrun

    prep_transpose<<<384, 256, 0, stream>>>(We1, We2, We3, W1T, W2T, W3T);
    prep_decoder<<<256, 256, 0, stream>>>(emb, Wd1, bd1, Wd2, bd2, Wd3, bd3, dec_out, en);
    vqvae_main<<<NROWS / 64, 512, 0, stream>>>(x, be1, be2, be3, W1T, W2T, W3T, emb, en,
                                               dec_out, out);
}

// Round 2
// 5190.070 us; speedup vs baseline: 1.0228x; 1.0228x over previous
//
#include <hip/hip_runtime.h>
#include <math.h>

#pragma clang fp contract(off)

#define NROWS 131072

// selu matching np: scale * where(x>0, x, alpha*expm1(x)), each op rounded separately
__device__ __forceinline__ float selu_f(float v) {
    float em  = expm1f(v);
    float neg = 1.6732632423543772f * em;
    float r   = v > 0.0f ? v : neg;
    return 1.0507009873554805f * r;
}

__device__ __forceinline__ float4 ldf4(const float* p) { return *(const float4*)p; }

__device__ __forceinline__ void ld2x4(float4* b, const float* p) { b[0] = ldf4(p); b[1] = ldf4(p + 4); }

__device__ __forceinline__ void fma8a(float* a, const float4* w, float h) {
    a[0] = __builtin_fmaf(w[0].x, h, a[0]);  a[1] = __builtin_fmaf(w[0].y, h, a[1]);
    a[2] = __builtin_fmaf(w[0].z, h, a[2]);  a[3] = __builtin_fmaf(w[0].w, h, a[3]);
    a[4] = __builtin_fmaf(w[1].x, h, a[4]);  a[5] = __builtin_fmaf(w[1].y, h, a[5]);
    a[6] = __builtin_fmaf(w[1].z, h, a[6]);  a[7] = __builtin_fmaf(w[1].w, h, a[7]);
}

// rotate step: issue next row's 2xf4 loads, then consume current buffer, then rotate in
__device__ __forceinline__ void step8(float* acc, float4* wb, const float* nextp, float h) {
    float4 t0 = ldf4(nextp), t1 = ldf4(nextp + 4);
    fma8a(acc, wb, h);
    wb[0] = t0; wb[1] = t1;
}

// ---------- prep 1: W2 [256,256] -> W2T [j][c]; W3 [64,256] -> W3T [c][e]; W1 [256,64] -> W1T [j][c]
__global__ void prep_transpose(const float* __restrict__ W1, const float* __restrict__ W2,
                               const float* __restrict__ W3,
                               float* __restrict__ W1T, float* __restrict__ W2T,
                               float* __restrict__ W3T) {
    int id = blockIdx.x * 256 + threadIdx.x;
    if (id < 65536) { int c = id >> 8, j = id & 255; W2T[j * 256 + c] = W2[id]; }
    int id2 = id - 65536;
    if (id2 >= 0 && id2 < 16384) { int e = id2 >> 8, c = id2 & 255; W3T[c * 64 + e] = W3[id2]; }
    int id3 = id - 81920;
    if (id3 >= 0 && id3 < 16384) { int c = id3 >> 6, j = id3 & 63; W1T[j * 256 + c] = W1[id3]; }
}

// ---------- prep 2: decoder table dec_out[k] = decoder(emb[k]), and en[k] = ||emb_k||^2 ----------
__global__ void prep_decoder(const float* __restrict__ emb,
                             const float* __restrict__ Wd1, const float* __restrict__ bd1,
                             const float* __restrict__ Wd2, const float* __restrict__ bd2,
                             const float* __restrict__ Wd3, const float* __restrict__ bd3,
                             float* __restrict__ dec_out, float* __restrict__ en) {
    __shared__ float e[64];
    __shared__ float h1[256];
    __shared__ float h2[256];
    const int t = threadIdx.x; // 256 threads
    for (int kc = 0; kc < 4; ++kc) {
        const int k = blockIdx.x * 4 + kc;
        __syncthreads();
        if (t < 64) e[t] = emb[k * 64 + t];
        __syncthreads();
        {
            float acc = 0.0f;
            const float* w = Wd1 + t * 64;
            #pragma unroll
            for (int j = 0; j < 64; ++j) acc = __builtin_fmaf(w[j], e[j], acc);
            h1[t] = selu_f(acc + bd1[t]);
        }
        __syncthreads();
        {
            float acc = 0.0f;
            const float* w = Wd2 + t * 256;
            #pragma unroll 8
            for (int j = 0; j < 256; ++j) acc = __builtin_fmaf(w[j], h1[j], acc);
            h2[t] = selu_f(acc + bd2[t]);
        }
        __syncthreads();
        if (t < 64) {
            float acc = 0.0f;
            const float* w = Wd3 + t * 256;
            #pragma unroll 8
            for (int j = 0; j < 256; ++j) acc = __builtin_fmaf(w[j], h2[j], acc);
            dec_out[k * 64 + t] = acc + bd3[t];
        }
        if (t == 0) {
            float r[8];
            #pragma unroll
            for (int u = 0; u < 8; ++u) r[u] = e[u] * e[u];
            #pragma unroll
            for (int i = 8; i < 64; i += 8) {
                #pragma unroll
                for (int u = 0; u < 8; ++u) { float p = e[i + u] * e[i + u]; r[u] = r[u] + p; }
            }
            en[k] = ((r[0] + r[1]) + (r[2] + r[3])) + ((r[4] + r[5]) + (r[6] + r[7]));
        }
    }
}

// ---------- main kernel ----------
// block = 512 threads = 8 waves, 64 rows (lane = row). Same 64-row tile / same 80 KB LDS as the
// 256-thread version, but twice the waves per LDS byte: 2 blocks/CU -> 16 waves/CU = 4 waves/SIMD.
// ROUND-1 LESSON: amdgpu_waves_per_eu(4) (min-only) let the allocator chase 8 waves/EU -> 64 VGPR
// -> 15 GB of scratch spill traffic per dispatch. Pin EXACTLY 4 with the two-arg form so the
// budget is 128 VGPRs (live peak ~100) and no spilling.
__global__ __launch_bounds__(512) __attribute__((amdgpu_waves_per_eu(4, 4)))
void vqvae_main(const float* __restrict__ x,
                const float* __restrict__ b1, const float* __restrict__ b2,
                const float* __restrict__ b3,
                const float* __restrict__ W1T, const float* __restrict__ W2T,
                const float* __restrict__ W3T,
                const float* __restrict__ emb, const float* __restrict__ en,
                const float* __restrict__ dec_out, float* __restrict__ out) {
    __shared__ __align__(16) float R1[16384];
    __shared__ __align__(16) float aux[4096];

    const int t    = threadIdx.x;
    const int wave = t >> 6;      // 0..7
    const int lane = t & 63;
    const size_t rowbase = (size_t)blockIdx.x * 64;

    // opaque zero in a VGPR: keeps uniform loads on the vector pipe (vmcnt, pipelinable)
    int lz;
    asm volatile("v_mov_b32 %0, 0" : "=v"(lz));

    const float* W1Tv = W1T + lz;
    const float* W2Tv = W2T + lz;
    const float* W3Tv = W3T + lz;
    const float* b1v  = b1 + lz;
    const float* b2v  = b2 + lz;
    const float* b3v  = b3 + lz;
    const float* env  = en + lz;
    const float* embv = emb + lz;

    // ---- phase 0: stage x tile transposed into aux: xT[j][r]
    #pragma unroll
    for (int q = 0; q < 2; ++q) {
        int f = t + 512 * q;
        int r = f >> 4, c4 = f & 15;
        float4 v = ldf4(x + (rowbase + r) * 64 + c4 * 4);
        aux[(c4 * 4 + 0) * 64 + r] = v.x;
        aux[(c4 * 4 + 1) * 64 + r] = v.y;
        aux[(c4 * 4 + 2) * 64 + r] = v.z;
        aux[(c4 * 4 + 3) * 64 + r] = v.w;
    }
    __syncthreads();

    // ---- phase 1: layer1. group g: this wave computes cols cg=64g+8*wave .. +8.
    // h1 stored as j-pairs: R1[(c>>1)*128 + lane*2 + (c&1)]
    for (int g = 0; g < 4; ++g) {
        const int cg = g * 64 + wave * 8;
        const float* wp = W1Tv + cg;      // row j at wp + j*256
        float4 A0[2], A1[2], A2[2], A3[2];
        ld2x4(A0, wp); ld2x4(A1, wp + 256); ld2x4(A2, wp + 512); ld2x4(A3, wp + 768);
        float acc[8];
        #pragma unroll
        for (int u = 0; u < 8; ++u) acc[u] = 0.0f;
        #pragma unroll 1
        for (int j = 0; j < 64; j += 4) {
            const float* np = wp + (j + 4) * 256;   // rows 64..67 overrun into W3T region (in-ws, unused)
            step8(acc, A0, np,        aux[(j + 0) * 64 + lane]);
            step8(acc, A1, np + 256,  aux[(j + 1) * 64 + lane]);
            step8(acc, A2, np + 512,  aux[(j + 2) * 64 + lane]);
            step8(acc, A3, np + 768,  aux[(j + 3) * 64 + lane]);
        }
        float bb[8];
        *(float4*)&bb[0] = ldf4(b1v + cg);
        *(float4*)&bb[4] = ldf4(b1v + cg + 4);
        float hv[8];
        #pragma unroll
        for (int u = 0; u < 8; ++u) hv[u] = selu_f(acc[u] + bb[u]);
        #pragma unroll
        for (int up = 0; up < 4; ++up) {
            *(float2*)&R1[((cg >> 1) + up) * 128 + (lane << 1)] = make_float2(hv[2 * up], hv[2 * up + 1]);
        }
    }
    __syncthreads();

    // ---- phase 2: layer2 + layer3, group-staged.
    // group g = col-block [64g, 64g+64): wave computes 8 cols (cg=64g+8*wave), stages h2 in aux,
    // then folds the whole 64-col block into its e-range er=[8*wave, +8) -> partial P_g.
    // z = ((P0+P1)+(P2+P3)) + b3  (identical chain to the passing rounds)
    const int er = wave * 8;
    float s01[8], s23[8];
    for (int g = 0; g < 4; ++g) {
        const int cg = g * 64 + wave * 8;
        const float* wp = W2Tv + cg;      // row j at wp + j*256
        float4 A0[2], A1[2], A2[2], A3[2];
        ld2x4(A0, wp); ld2x4(A1, wp + 256); ld2x4(A2, wp + 512); ld2x4(A3, wp + 768);
        float acc[8];
        #pragma unroll
        for (int u = 0; u < 8; ++u) acc[u] = 0.0f;
        #pragma unroll 1
        for (int j = 0; j < 256; j += 4) {
            const float* np = wp + (j + 4) * 256; // rows 256..259 land in W1T region (in-ws, unused)
            float2 h01 = *(const float2*)&R1[(j >> 1) * 128 + (lane << 1)];
            step8(acc, A0, np,        h01.x);
            step8(acc, A1, np + 256,  h01.y);
            float2 h23 = *(const float2*)&R1[((j >> 1) + 1) * 128 + (lane << 1)];
            step8(acc, A2, np + 512,  h23.x);
            step8(acc, A3, np + 768,  h23.y);
        }
        __syncthreads();   // previous fold's readers of aux are done
        {
            float bb[8];
            *(float4*)&bb[0] = ldf4(b2v + cg);
            *(float4*)&bb[4] = ldf4(b2v + cg + 4);
            #pragma unroll
            for (int u = 0; u < 8; ++u)
                aux[(wave * 8 + u) * 64 + lane] = selu_f(acc[u] + bb[u]);
        }
        __syncthreads();   // h2 of this col-block visible
        // fold col-block g (cols 64g..64g+63 ascending) into e-range er..er+8
        const float* w3p = W3Tv + g * 4096 + er;    // col (64g+c) at w3p + c*64
        float4 F0[2], F1[2], F2[2], F3[2];
        ld2x4(F0, w3p); ld2x4(F1, w3p + 64); ld2x4(F2, w3p + 128); ld2x4(F3, w3p + 192);
        float P[8];
        #pragma unroll
        for (int u = 0; u < 8; ++u) P[u] = 0.0f;
        #pragma unroll 1
        for (int c = 0; c < 64; c += 4) {
            const float* np = w3p + (c + 4) * 64;  // col 64..67 overrun into en pad (in-ws)
            step8(P, F0, np,        aux[(c + 0) * 64 + lane]);
            step8(P, F1, np + 64,   aux[(c + 1) * 64 + lane]);
            step8(P, F2, np + 128,  aux[(c + 2) * 64 + lane]);
            step8(P, F3, np + 192,  aux[(c + 3) * 64 + lane]);
        }
        if (g == 0) {
            #pragma unroll
            for (int u = 0; u < 8; ++u) s01[u] = P[u];
        } else if (g == 1) {
            #pragma unroll
            for (int u = 0; u < 8; ++u) s01[u] = s01[u] + P[u];
        } else if (g == 2) {
            #pragma unroll
            for (int u = 0; u < 8; ++u) s23[u] = P[u];
        } else {
            #pragma unroll
            for (int u = 0; u < 8; ++u) s23[u] = s23[u] + P[u];
        }
    }

    // ---- phase 3: z = (s01+s23)+b3; park z in LDS (zs[lane][e], stride 68 -> 2-way free b128)
    {
        float bb[8];
        *(float4*)&bb[0] = ldf4(b3v + er);
        *(float4*)&bb[4] = ldf4(b3v + er + 4);
        float zv[8];
        #pragma unroll
        for (int u = 0; u < 8; ++u) zv[u] = (s01[u] + s23[u]) + bb[u];
        *(float4*)&R1[lane * 68 + er]     = make_float4(zv[0], zv[1], zv[2], zv[3]);
        *(float4*)&R1[lane * 68 + er + 4] = make_float4(zv[4], zv[5], zv[6], zv[7]);
    }
    __syncthreads();

    // A = ||z||^2 with numpy pairwise chain (8 strided accumulators, balanced tree)
    float A;
    {
        float z[64];
        #pragma unroll
        for (int m = 0; m < 16; ++m) {
            float4 v = *(const float4*)&R1[lane * 68 + m * 4];
            z[4 * m] = v.x; z[4 * m + 1] = v.y; z[4 * m + 2] = v.z; z[4 * m + 3] = v.w;
        }
        float r[8];
        #pragma unroll
        for (int u = 0; u < 8; ++u) r[u] = z[u] * z[u];
        #pragma unroll
        for (int i = 8; i < 64; i += 8) {
            #pragma unroll
            for (int u = 0; u < 8; ++u) { float p = z[i + u] * z[i + u]; r[u] = r[u] + p; }
        }
        A = ((r[0] + r[1]) + (r[2] + r[3])) + ((r[4] + r[5]) + (r[6] + r[7]));
    }

    // ---- phase 4: scores over wave's 128-code slice, 8-code chunks, z quarters re-read from LDS
    float best = 3.4e38f;
    const int k0 = wave * 128;
    int bk = k0;
    const float* embw = embv + (size_t)k0 * 64;
    #pragma unroll 1
    for (int kc = 0; kc < 128; kc += 8) {
        float4 en03 = ldf4(env + k0 + kc);
        float4 en47 = ldf4(env + k0 + kc + 4);
        float d0[8], d1[8], d2[8], d3[8];
        #pragma unroll
        for (int c = 0; c < 8; ++c) { d0[c] = 0.f; d1[c] = 0.f; d2[c] = 0.f; d3[c] = 0.f; }
        #pragma unroll
        for (int q = 0; q < 4; ++q) {
            float4 zq0 = *(const float4*)&R1[lane * 68 + q * 16];
            float4 zq1 = *(const float4*)&R1[lane * 68 + q * 16 + 4];
            float4 zq2 = *(const float4*)&R1[lane * 68 + q * 16 + 8];
            float4 zq3 = *(const float4*)&R1[lane * 68 + q * 16 + 12];
            #pragma unroll
            for (int c = 0; c < 8; ++c) {
                const float* ep = embw + (kc + c) * 64 + q * 16;
                float4 e0 = ldf4(ep), e1 = ldf4(ep + 4), e2 = ldf4(ep + 8), e3 = ldf4(ep + 12);
                d0[c] = __builtin_fmaf(zq0.x, e0.x, d0[c]);
                d1[c] = __builtin_fmaf(zq0.y, e0.y, d1[c]);
                d2[c] = __builtin_fmaf(zq0.z, e0.z, d2[c]);
                d3[c] = __builtin_fmaf(zq0.w, e0.w, d3[c]);
                d0[c] = __builtin_fmaf(zq1.x, e1.x, d0[c]);
                d1[c] = __builtin_fmaf(zq1.y, e1.y, d1[c]);
                d2[c] = __builtin_fmaf(zq1.z, e1.z, d2[c]);
                d3[c] = __builtin_fmaf(zq1.w, e1.w, d3[c]);
                d0[c] = __builtin_fmaf(zq2.x, e2.x, d0[c]);
                d1[c] = __builtin_fmaf(zq2.y, e2.y, d1[c]);
                d2[c] = __builtin_fmaf(zq2.z, e2.z, d2[c]);
                d3[c] = __builtin_fmaf(zq2.w, e2.w, d3[c]);
                d0[c] = __builtin_fmaf(zq3.x, e3.x, d0[c]);
                d1[c] = __builtin_fmaf(zq3.y, e3.y, d1[c]);
                d2[c] = __builtin_fmaf(zq3.z, e3.z, d2[c]);
                d3[c] = __builtin_fmaf(zq3.w, e3.w, d3[c]);
            }
        }
        float enb[8];
        *(float4*)&enb[0] = en03; *(float4*)&enb[4] = en47;
        #pragma unroll
        for (int c = 0; c < 8; ++c) {
            float dot = (d0[c] + d1[c]) + (d2[c] + d3[c]);
            float tt  = __builtin_fmaf(-2.0f, dot, A);
            float s   = tt + enb[c];
            if (s < best) { best = s; bk = k0 + kc + c; }
        }
    }

    // ---- phase 5: cross-wave argmin (ascending wave => first-min); aux now dead -> cand storage
    float* cand_s = aux + 64;             // 512 floats
    int*   cand_k = ((int*)aux) + 576;    // 512 ints
    int*   ixp    = (int*)aux;            // 64 ints
    cand_s[wave * 64 + lane] = best;
    cand_k[wave * 64 + lane] = bk;
    __syncthreads();
    if (t < 64) {
        float s0 = cand_s[t];
        int   kk = cand_k[t];
        #pragma unroll
        for (int w2 = 1; w2 < 8; ++w2) {
            float sw = cand_s[w2 * 64 + t];
            if (sw < s0) { s0 = sw; kk = cand_k[w2 * 64 + t]; }
        }
        ixp[t] = kk;
        out[(size_t)NROWS * 64 + rowbase + t] = (float)kk;
    }
    __syncthreads();

    // ---- phase 6: recon = dec_out[idx], coalesced f4 store
    #pragma unroll
    for (int q = 0; q < 2; ++q) {
        int f = t + 512 * q;
        int r = f >> 4, c4 = f & 15;
        float4 v = ldf4(dec_out + (size_t)ixp[r] * 64 + c4 * 4);
        *(float4*)(out + (rowbase + r) * 64 + c4 * 4) = v;
    }
}

extern "C" void kernel_launch(void* const* d_in, const int* in_sizes, int n_in,
                              void* d_out, int out_size, void* d_ws, size_t ws_size,
                              hipStream_t stream) {
    const float* x   = (const float*)d_in[0];
    const float* We1 = (const float*)d_in[1];
    const float* be1 = (const float*)d_in[2];
    const float* We2 = (const float*)d_in[3];
    const float* be2 = (const float*)d_in[4];
    const float* We3 = (const float*)d_in[5];
    const float* be3 = (const float*)d_in[6];
    const float* emb = (const float*)d_in[7];
    const float* Wd1 = (const float*)d_in[8];
    const float* bd1 = (const float*)d_in[9];
    const float* Wd2 = (const float*)d_in[10];
    const float* bd2 = (const float*)d_in[11];
    const float* Wd3 = (const float*)d_in[12];
    const float* bd3 = (const float*)d_in[13];
    float* out = (float*)d_out;

    // ws layout (floats): dec_out[65536] | W2T[65536] | W1T[16384] | W3T[16384] | en[1024+pad]
    float* ws      = (float*)d_ws;
    float* dec_out = ws;
    float* W2T     = ws + 65536;
    float* W1T     = ws + 131072;
    float* W3T     = ws + 147456;
    float* en      = ws + 163840;   // en + 1 KB pad absorbs fold prefetch overrun

    prep_transpose<<<384, 256, 0, stream>>>(We1, We2, We3, W1T, W2T, W3T);
    prep_decoder<<<256, 256, 0, stream>>>(emb, Wd1, bd1, Wd2, bd2, Wd3, bd3, dec_out, en);
    vqvae_main<<<NROWS / 64, 512, 0, stream>>>(x, be1, be2, be3, W1T, W2T, W3T, emb, en,
                                               dec_out, out);
}

// Round 3
// 3472.665 us; speedup vs baseline: 1.5286x; 1.4945x over previous
//
#include <hip/hip_runtime.h>
#include <math.h>

#pragma clang fp contract(off)

#define NROWS 131072

// selu matching np: scale * where(x>0, x, alpha*expm1(x)), each op rounded separately
__device__ __forceinline__ float selu_f(float v) {
    float em  = expm1f(v);
    float neg = 1.6732632423543772f * em;
    float r   = v > 0.0f ? v : neg;
    return 1.0507009873554805f * r;
}

__device__ __forceinline__ float4 ldf4(const float* p) { return *(const float4*)p; }

__device__ __forceinline__ void ld2x4(float4* b, const float* p) { b[0] = ldf4(p); b[1] = ldf4(p + 4); }

__device__ __forceinline__ void fma8a(float* a, const float4* w, float h) {
    a[0] = __builtin_fmaf(w[0].x, h, a[0]);  a[1] = __builtin_fmaf(w[0].y, h, a[1]);
    a[2] = __builtin_fmaf(w[0].z, h, a[2]);  a[3] = __builtin_fmaf(w[0].w, h, a[3]);
    a[4] = __builtin_fmaf(w[1].x, h, a[4]);  a[5] = __builtin_fmaf(w[1].y, h, a[5]);
    a[6] = __builtin_fmaf(w[1].z, h, a[6]);  a[7] = __builtin_fmaf(w[1].w, h, a[7]);
}

// rotate step: issue next row's 2xf4 loads, then consume current buffer, then rotate in
__device__ __forceinline__ void step8(float* acc, float4* wb, const float* nextp, float h) {
    float4 t0 = ldf4(nextp), t1 = ldf4(nextp + 4);
    fma8a(acc, wb, h);
    wb[0] = t0; wb[1] = t1;
}

// ---------- prep 1: W2 [256,256] -> W2T [j][c]; W3 [64,256] -> W3T [c][e]; W1 [256,64] -> W1T [j][c]
__global__ void prep_transpose(const float* __restrict__ W1, const float* __restrict__ W2,
                               const float* __restrict__ W3,
                               float* __restrict__ W1T, float* __restrict__ W2T,
                               float* __restrict__ W3T) {
    int id = blockIdx.x * 256 + threadIdx.x;
    if (id < 65536) { int c = id >> 8, j = id & 255; W2T[j * 256 + c] = W2[id]; }
    int id2 = id - 65536;
    if (id2 >= 0 && id2 < 16384) { int e = id2 >> 8, c = id2 & 255; W3T[c * 64 + e] = W3[id2]; }
    int id3 = id - 81920;
    if (id3 >= 0 && id3 < 16384) { int c = id3 >> 6, j = id3 & 63; W1T[j * 256 + c] = W1[id3]; }
}

// ---------- prep 2: decoder table dec_out[k] = decoder(emb[k]), and en[k] = ||emb_k||^2 ----------
__global__ void prep_decoder(const float* __restrict__ emb,
                             const float* __restrict__ Wd1, const float* __restrict__ bd1,
                             const float* __restrict__ Wd2, const float* __restrict__ bd2,
                             const float* __restrict__ Wd3, const float* __restrict__ bd3,
                             float* __restrict__ dec_out, float* __restrict__ en) {
    __shared__ float e[64];
    __shared__ float h1[256];
    __shared__ float h2[256];
    const int t = threadIdx.x; // 256 threads
    for (int kc = 0; kc < 4; ++kc) {
        const int k = blockIdx.x * 4 + kc;
        __syncthreads();
        if (t < 64) e[t] = emb[k * 64 + t];
        __syncthreads();
        {
            float acc = 0.0f;
            const float* w = Wd1 + t * 64;
            #pragma unroll
            for (int j = 0; j < 64; ++j) acc = __builtin_fmaf(w[j], e[j], acc);
            h1[t] = selu_f(acc + bd1[t]);
        }
        __syncthreads();
        {
            float acc = 0.0f;
            const float* w = Wd2 + t * 256;
            #pragma unroll 8
            for (int j = 0; j < 256; ++j) acc = __builtin_fmaf(w[j], h1[j], acc);
            h2[t] = selu_f(acc + bd2[t]);
        }
        __syncthreads();
        if (t < 64) {
            float acc = 0.0f;
            const float* w = Wd3 + t * 256;
            #pragma unroll 8
            for (int j = 0; j < 256; ++j) acc = __builtin_fmaf(w[j], h2[j], acc);
            dec_out[k * 64 + t] = acc + bd3[t];
        }
        if (t == 0) {
            float r[8];
            #pragma unroll
            for (int u = 0; u < 8; ++u) r[u] = e[u] * e[u];
            #pragma unroll
            for (int i = 8; i < 64; i += 8) {
                #pragma unroll
                for (int u = 0; u < 8; ++u) { float p = e[i + u] * e[i + u]; r[u] = r[u] + p; }
            }
            en[k] = ((r[0] + r[1]) + (r[2] + r[3])) + ((r[4] + r[5]) + (r[6] + r[7]));
        }
    }
}

// ---------- main kernel ----------
// block = 512 threads = 8 waves, 64 rows (lane = row). 80 KB LDS -> 2 blocks/CU = 16 waves/CU
// = 4 waves/SIMD (LDS-capped regardless of VGPRs).
// ROUND-1/2 LESSON: the allocator pins this kernel at a 64-VGPR budget no matter what
// waves_per_eu attributes say; the old phase-3 (z[64] in regs) and phase-4 (32 d-accums)
// exceeded it -> 15 GB scratch spill traffic = the whole runtime. Fix: keep live regs <= ~60
// EVERYWHERE so a 64-VGPR allocation spills nothing:
//   - phase-2 j-loop + fold: 2 weight streams instead of 4 (j/c order unchanged -> bit-exact)
//   - phase-3 ||z||^2: stream octets from LDS, never materialize z[64]
//   - phase-4: 4-code chunks (16 d-accums) instead of 8-code (32)
__global__ __launch_bounds__(512, 4)
void vqvae_main(const float* __restrict__ x,
                const float* __restrict__ b1, const float* __restrict__ b2,
                const float* __restrict__ b3,
                const float* __restrict__ W1T, const float* __restrict__ W2T,
                const float* __restrict__ W3T,
                const float* __restrict__ emb, const float* __restrict__ en,
                const float* __restrict__ dec_out, float* __restrict__ out) {
    __shared__ __align__(16) float R1[16384];
    __shared__ __align__(16) float aux[4096];

    const int t    = threadIdx.x;
    const int wave = t >> 6;      // 0..7
    const int lane = t & 63;
    const size_t rowbase = (size_t)blockIdx.x * 64;

    // opaque zero in a VGPR: keeps uniform loads on the vector pipe (vmcnt, pipelinable)
    int lz;
    asm volatile("v_mov_b32 %0, 0" : "=v"(lz));

    const float* W1Tv = W1T + lz;
    const float* W2Tv = W2T + lz;
    const float* W3Tv = W3T + lz;
    const float* b1v  = b1 + lz;
    const float* b2v  = b2 + lz;
    const float* b3v  = b3 + lz;
    const float* env  = en + lz;
    const float* embv = emb + lz;

    // ---- phase 0: stage x tile transposed into aux: xT[j][r]
    #pragma unroll
    for (int q = 0; q < 2; ++q) {
        int f = t + 512 * q;
        int r = f >> 4, c4 = f & 15;
        float4 v = ldf4(x + (rowbase + r) * 64 + c4 * 4);
        aux[(c4 * 4 + 0) * 64 + r] = v.x;
        aux[(c4 * 4 + 1) * 64 + r] = v.y;
        aux[(c4 * 4 + 2) * 64 + r] = v.z;
        aux[(c4 * 4 + 3) * 64 + r] = v.w;
    }
    __syncthreads();

    // ---- phase 1: layer1. group g: this wave computes cols cg=64g+8*wave .. +8.
    // h1 stored as j-pairs: R1[(c>>1)*128 + lane*2 + (c&1)]
    // 4 streams here (no s01/s23 live yet): ~56 live regs.
    for (int g = 0; g < 4; ++g) {
        const int cg = g * 64 + wave * 8;
        const float* wp = W1Tv + cg;      // row j at wp + j*256
        float4 A0[2], A1[2], A2[2], A3[2];
        ld2x4(A0, wp); ld2x4(A1, wp + 256); ld2x4(A2, wp + 512); ld2x4(A3, wp + 768);
        float acc[8];
        #pragma unroll
        for (int u = 0; u < 8; ++u) acc[u] = 0.0f;
        #pragma unroll 1
        for (int j = 0; j < 64; j += 4) {
            const float* np = wp + (j + 4) * 256;   // rows 64..67 overrun into W3T region (in-ws, unused)
            step8(acc, A0, np,        aux[(j + 0) * 64 + lane]);
            step8(acc, A1, np + 256,  aux[(j + 1) * 64 + lane]);
            step8(acc, A2, np + 512,  aux[(j + 2) * 64 + lane]);
            step8(acc, A3, np + 768,  aux[(j + 3) * 64 + lane]);
        }
        float bb[8];
        *(float4*)&bb[0] = ldf4(b1v + cg);
        *(float4*)&bb[4] = ldf4(b1v + cg + 4);
        float hv[8];
        #pragma unroll
        for (int u = 0; u < 8; ++u) hv[u] = selu_f(acc[u] + bb[u]);
        #pragma unroll
        for (int up = 0; up < 4; ++up) {
            *(float2*)&R1[((cg >> 1) + up) * 128 + (lane << 1)] = make_float2(hv[2 * up], hv[2 * up + 1]);
        }
    }
    __syncthreads();

    // ---- phase 2: layer2 + layer3, group-staged.
    // group g = col-block [64g, 64g+64): wave computes 8 cols (cg=64g+8*wave), stages h2 in aux,
    // then folds the whole 64-col block into its e-range er=[8*wave, +8) -> partial P_g.
    // z = ((P0+P1)+(P2+P3)) + b3  (identical chain to the passing rounds)
    // 2 weight streams (A0,A1 / F0,F1): j and c remain strictly ascending -> bit-exact.
    const int er = wave * 8;
    float s01[8], s23[8];
    for (int g = 0; g < 4; ++g) {
        const int cg = g * 64 + wave * 8;
        const float* wp = W2Tv + cg;      // row j at wp + j*256
        float4 A0[2], A1[2];
        ld2x4(A0, wp); ld2x4(A1, wp + 256);
        float acc[8];
        #pragma unroll
        for (int u = 0; u < 8; ++u) acc[u] = 0.0f;
        #pragma unroll 1
        for (int j = 0; j < 256; j += 2) {
            const float* np = wp + (j + 2) * 256; // rows 256..257 land in W1T region (in-ws, unused)
            float2 h01 = *(const float2*)&R1[(j >> 1) * 128 + (lane << 1)];
            step8(acc, A0, np,        h01.x);
            step8(acc, A1, np + 256,  h01.y);
        }
        __syncthreads();   // previous fold's readers of aux are done
        {
            float bb[8];
            *(float4*)&bb[0] = ldf4(b2v + cg);
            *(float4*)&bb[4] = ldf4(b2v + cg + 4);
            #pragma unroll
            for (int u = 0; u < 8; ++u)
                aux[(wave * 8 + u) * 64 + lane] = selu_f(acc[u] + bb[u]);
        }
        __syncthreads();   // h2 of this col-block visible
        // fold col-block g (cols 64g..64g+63 ascending) into e-range er..er+8
        const float* w3p = W3Tv + g * 4096 + er;    // col (64g+c) at w3p + c*64
        float4 F0[2], F1[2];
        ld2x4(F0, w3p); ld2x4(F1, w3p + 64);
        float P[8];
        #pragma unroll
        for (int u = 0; u < 8; ++u) P[u] = 0.0f;
        #pragma unroll 1
        for (int c = 0; c < 64; c += 2) {
            const float* np = w3p + (c + 2) * 64;  // cols 64..65 overrun into en pad (in-ws)
            step8(P, F0, np,       aux[(c + 0) * 64 + lane]);
            step8(P, F1, np + 64,  aux[(c + 1) * 64 + lane]);
        }
        if (g == 0) {
            #pragma unroll
            for (int u = 0; u < 8; ++u) s01[u] = P[u];
        } else if (g == 1) {
            #pragma unroll
            for (int u = 0; u < 8; ++u) s01[u] = s01[u] + P[u];
        } else if (g == 2) {
            #pragma unroll
            for (int u = 0; u < 8; ++u) s23[u] = P[u];
        } else {
            #pragma unroll
            for (int u = 0; u < 8; ++u) s23[u] = s23[u] + P[u];
        }
    }

    // ---- phase 3: z = (s01+s23)+b3; park z in LDS (zs[lane][e], stride 68 -> 2-way free b128)
    {
        float bb[8];
        *(float4*)&bb[0] = ldf4(b3v + er);
        *(float4*)&bb[4] = ldf4(b3v + er + 4);
        float zv[8];
        #pragma unroll
        for (int u = 0; u < 8; ++u) zv[u] = (s01[u] + s23[u]) + bb[u];
        *(float4*)&R1[lane * 68 + er]     = make_float4(zv[0], zv[1], zv[2], zv[3]);
        *(float4*)&R1[lane * 68 + er + 4] = make_float4(zv[4], zv[5], zv[6], zv[7]);
    }
    __syncthreads();

    // A = ||z||^2 with numpy pairwise chain (8 strided accumulators, balanced tree).
    // Streamed in octets from LDS -- never holds z[64] in registers (live ~20).
    float A;
    {
        float r[8];
        {
            float4 v0 = *(const float4*)&R1[lane * 68 + 0];
            float4 v1 = *(const float4*)&R1[lane * 68 + 4];
            r[0] = v0.x * v0.x; r[1] = v0.y * v0.y; r[2] = v0.z * v0.z; r[3] = v0.w * v0.w;
            r[4] = v1.x * v1.x; r[5] = v1.y * v1.y; r[6] = v1.z * v1.z; r[7] = v1.w * v1.w;
        }
        #pragma unroll
        for (int i = 8; i < 64; i += 8) {
            float4 v0 = *(const float4*)&R1[lane * 68 + i];
            float4 v1 = *(const float4*)&R1[lane * 68 + i + 4];
            float p0 = v0.x * v0.x, p1 = v0.y * v0.y, p2 = v0.z * v0.z, p3 = v0.w * v0.w;
            float p4 = v1.x * v1.x, p5 = v1.y * v1.y, p6 = v1.z * v1.z, p7 = v1.w * v1.w;
            r[0] = r[0] + p0; r[1] = r[1] + p1; r[2] = r[2] + p2; r[3] = r[3] + p3;
            r[4] = r[4] + p4; r[5] = r[5] + p5; r[6] = r[6] + p6; r[7] = r[7] + p7;
        }
        A = ((r[0] + r[1]) + (r[2] + r[3])) + ((r[4] + r[5]) + (r[6] + r[7]));
    }

    // ---- phase 4: scores over wave's 128-code slice, 4-code chunks (16 d-accums, live ~56),
    // z quarters re-read from LDS. Per-code FMA order identical to previous rounds.
    float best = 3.4e38f;
    const int k0 = wave * 128;
    int bk = k0;
    const float* embw = embv + (size_t)k0 * 64;
    #pragma unroll 1
    for (int kc = 0; kc < 128; kc += 4) {
        float4 en03 = ldf4(env + k0 + kc);
        float d0[4], d1[4], d2[4], d3[4];
        #pragma unroll
        for (int c = 0; c < 4; ++c) { d0[c] = 0.f; d1[c] = 0.f; d2[c] = 0.f; d3[c] = 0.f; }
        #pragma unroll
        for (int q = 0; q < 4; ++q) {
            float4 zq0 = *(const float4*)&R1[lane * 68 + q * 16];
            float4 zq1 = *(const float4*)&R1[lane * 68 + q * 16 + 4];
            float4 zq2 = *(const float4*)&R1[lane * 68 + q * 16 + 8];
            float4 zq3 = *(const float4*)&R1[lane * 68 + q * 16 + 12];
            #pragma unroll
            for (int c = 0; c < 4; ++c) {
                const float* ep = embw + (kc + c) * 64 + q * 16;
                float4 e0 = ldf4(ep), e1 = ldf4(ep + 4), e2 = ldf4(ep + 8), e3 = ldf4(ep + 12);
                d0[c] = __builtin_fmaf(zq0.x, e0.x, d0[c]);
                d1[c] = __builtin_fmaf(zq0.y, e0.y, d1[c]);
                d2[c] = __builtin_fmaf(zq0.z, e0.z, d2[c]);
                d3[c] = __builtin_fmaf(zq0.w, e0.w, d3[c]);
                d0[c] = __builtin_fmaf(zq1.x, e1.x, d0[c]);
                d1[c] = __builtin_fmaf(zq1.y, e1.y, d1[c]);
                d2[c] = __builtin_fmaf(zq1.z, e1.z, d2[c]);
                d3[c] = __builtin_fmaf(zq1.w, e1.w, d3[c]);
                d0[c] = __builtin_fmaf(zq2.x, e2.x, d0[c]);
                d1[c] = __builtin_fmaf(zq2.y, e2.y, d1[c]);
                d2[c] = __builtin_fmaf(zq2.z, e2.z, d2[c]);
                d3[c] = __builtin_fmaf(zq2.w, e2.w, d3[c]);
                d0[c] = __builtin_fmaf(zq3.x, e3.x, d0[c]);
                d1[c] = __builtin_fmaf(zq3.y, e3.y, d1[c]);
                d2[c] = __builtin_fmaf(zq3.z, e3.z, d2[c]);
                d3[c] = __builtin_fmaf(zq3.w, e3.w, d3[c]);
            }
        }
        float enb[4];
        *(float4*)&enb[0] = en03;
        #pragma unroll
        for (int c = 0; c < 4; ++c) {
            float dot = (d0[c] + d1[c]) + (d2[c] + d3[c]);
            float tt  = __builtin_fmaf(-2.0f, dot, A);
            float s   = tt + enb[c];
            if (s < best) { best = s; bk = k0 + kc + c; }
        }
    }

    // ---- phase 5: cross-wave argmin (ascending wave => first-min); aux now dead -> cand storage
    float* cand_s = aux + 64;             // 512 floats
    int*   cand_k = ((int*)aux) + 576;    // 512 ints
    int*   ixp    = (int*)aux;            // 64 ints
    cand_s[wave * 64 + lane] = best;
    cand_k[wave * 64 + lane] = bk;
    __syncthreads();
    if (t < 64) {
        float s0 = cand_s[t];
        int   kk = cand_k[t];
        #pragma unroll
        for (int w2 = 1; w2 < 8; ++w2) {
            float sw = cand_s[w2 * 64 + t];
            if (sw < s0) { s0 = sw; kk = cand_k[w2 * 64 + t]; }
        }
        ixp[t] = kk;
        out[(size_t)NROWS * 64 + rowbase + t] = (float)kk;
    }
    __syncthreads();

    // ---- phase 6: recon = dec_out[idx], coalesced f4 store
    #pragma unroll
    for (int q = 0; q < 2; ++q) {
        int f = t + 512 * q;
        int r = f >> 4, c4 = f & 15;
        float4 v = ldf4(dec_out + (size_t)ixp[r] * 64 + c4 * 4);
        *(float4*)(out + (rowbase + r) * 64 + c4 * 4) = v;
    }
}

extern "C" void kernel_launch(void* const* d_in, const int* in_sizes, int n_in,
                              void* d_out, int out_size, void* d_ws, size_t ws_size,
                              hipStream_t stream) {
    const float* x   = (const float*)d_in[0];
    const float* We1 = (const float*)d_in[1];
    const float* be1 = (const float*)d_in[2];
    const float* We2 = (const float*)d_in[3];
    const float* be2 = (const float*)d_in[4];
    const float* We3 = (const float*)d_in[5];
    const float* be3 = (const float*)d_in[6];
    const float* emb = (const float*)d_in[7];
    const float* Wd1 = (const float*)d_in[8];
    const float* bd1 = (const float*)d_in[9];
    const float* Wd2 = (const float*)d_in[10];
    const float* bd2 = (const float*)d_in[11];
    const float* Wd3 = (const float*)d_in[12];
    const float* bd3 = (const float*)d_in[13];
    float* out = (float*)d_out;

    // ws layout (floats): dec_out[65536] | W2T[65536] | W1T[16384] | W3T[16384] | en[1024+pad]
    float* ws      = (float*)d_ws;
    float* dec_out = ws;
    float* W2T     = ws + 65536;
    float* W1T     = ws + 131072;
    float* W3T     = ws + 147456;
    float* en      = ws + 163840;   // en + 1 KB pad absorbs fold prefetch overrun

    prep_transpose<<<384, 256, 0, stream>>>(We1, We2, We3, W1T, W2T, W3T);
    prep_decoder<<<256, 256, 0, stream>>>(emb, Wd1, bd1, Wd2, bd2, Wd3, bd3, dec_out, en);
    vqvae_main<<<NROWS / 64, 512, 0, stream>>>(x, be1, be2, be3, W1T, W2T, W3T, emb, en,
                                               dec_out, out);
}

// Round 6
// 2506.903 us; speedup vs baseline: 2.1175x; 1.3852x over previous
//
#include <hip/hip_runtime.h>
#include <math.h>

#pragma clang fp contract(off)

#define NROWS 131072

// selu matching np: scale * where(x>0, x, alpha*expm1(x)), each op rounded separately
__device__ __forceinline__ float selu_f(float v) {
    float em  = expm1f(v);
    float neg = 1.6732632423543772f * em;
    float r   = v > 0.0f ? v : neg;
    return 1.0507009873554805f * r;
}

__device__ __forceinline__ float4 ldf4(const float* p) { return *(const float4*)p; }

__device__ __forceinline__ void ld4x4(float4* b, const float* p) {
    b[0] = ldf4(p); b[1] = ldf4(p + 4); b[2] = ldf4(p + 8); b[3] = ldf4(p + 12);
}

__device__ __forceinline__ void fma16a(float* a, const float4* w, float h) {
    a[0]  = __builtin_fmaf(w[0].x, h, a[0]);  a[1]  = __builtin_fmaf(w[0].y, h, a[1]);
    a[2]  = __builtin_fmaf(w[0].z, h, a[2]);  a[3]  = __builtin_fmaf(w[0].w, h, a[3]);
    a[4]  = __builtin_fmaf(w[1].x, h, a[4]);  a[5]  = __builtin_fmaf(w[1].y, h, a[5]);
    a[6]  = __builtin_fmaf(w[1].z, h, a[6]);  a[7]  = __builtin_fmaf(w[1].w, h, a[7]);
    a[8]  = __builtin_fmaf(w[2].x, h, a[8]);  a[9]  = __builtin_fmaf(w[2].y, h, a[9]);
    a[10] = __builtin_fmaf(w[2].z, h, a[10]); a[11] = __builtin_fmaf(w[2].w, h, a[11]);
    a[12] = __builtin_fmaf(w[3].x, h, a[12]); a[13] = __builtin_fmaf(w[3].y, h, a[13]);
    a[14] = __builtin_fmaf(w[3].z, h, a[14]); a[15] = __builtin_fmaf(w[3].w, h, a[15]);
}

// rotate step: issue next row's 4xf4 loads, then consume current buffer, then rotate in
__device__ __forceinline__ void step16(float* acc, float4* wb, const float* nextp, float h) {
    float4 t0 = ldf4(nextp), t1 = ldf4(nextp + 4), t2 = ldf4(nextp + 8), t3 = ldf4(nextp + 12);
    fma16a(acc, wb, h);
    wb[0] = t0; wb[1] = t1; wb[2] = t2; wb[3] = t3;
}

// 16 fmas from 4 explicit float4s (immediate-consume form, no rotate buffer)
__device__ __forceinline__ void fma16q(float* a, float4 w0, float4 w1, float4 w2, float4 w3, float h) {
    a[0]  = __builtin_fmaf(w0.x, h, a[0]);  a[1]  = __builtin_fmaf(w0.y, h, a[1]);
    a[2]  = __builtin_fmaf(w0.z, h, a[2]);  a[3]  = __builtin_fmaf(w0.w, h, a[3]);
    a[4]  = __builtin_fmaf(w1.x, h, a[4]);  a[5]  = __builtin_fmaf(w1.y, h, a[5]);
    a[6]  = __builtin_fmaf(w1.z, h, a[6]);  a[7]  = __builtin_fmaf(w1.w, h, a[7]);
    a[8]  = __builtin_fmaf(w2.x, h, a[8]);  a[9]  = __builtin_fmaf(w2.y, h, a[9]);
    a[10] = __builtin_fmaf(w2.z, h, a[10]); a[11] = __builtin_fmaf(w2.w, h, a[11]);
    a[12] = __builtin_fmaf(w3.x, h, a[12]); a[13] = __builtin_fmaf(w3.y, h, a[13]);
    a[14] = __builtin_fmaf(w3.z, h, a[14]); a[15] = __builtin_fmaf(w3.w, h, a[15]);
}

// ---------- prep 1: W2 [256,256] -> W2T [j][c]; W3 [64,256] -> W3T [c][e]; W1 [256,64] -> W1T [j][c]
__global__ void prep_transpose(const float* __restrict__ W1, const float* __restrict__ W2,
                               const float* __restrict__ W3,
                               float* __restrict__ W1T, float* __restrict__ W2T,
                               float* __restrict__ W3T) {
    int id = blockIdx.x * 256 + threadIdx.x;
    if (id < 65536) { int c = id >> 8, j = id & 255; W2T[j * 256 + c] = W2[id]; }
    int id2 = id - 65536;
    if (id2 >= 0 && id2 < 16384) { int e = id2 >> 8, c = id2 & 255; W3T[c * 64 + e] = W3[id2]; }
    int id3 = id - 81920;
    if (id3 >= 0 && id3 < 16384) { int c = id3 >> 6, j = id3 & 63; W1T[j * 256 + c] = W1[id3]; }
}

// ---------- prep 2: decoder table dec_out[k] = decoder(emb[k]), and en[k] = ||emb_k||^2 ----------
__global__ void prep_decoder(const float* __restrict__ emb,
                             const float* __restrict__ Wd1, const float* __restrict__ bd1,
                             const float* __restrict__ Wd2, const float* __restrict__ bd2,
                             const float* __restrict__ Wd3, const float* __restrict__ bd3,
                             float* __restrict__ dec_out, float* __restrict__ en) {
    __shared__ float e[64];
    __shared__ float h1[256];
    __shared__ float h2[256];
    const int t = threadIdx.x; // 256 threads
    for (int kc = 0; kc < 4; ++kc) {
        const int k = blockIdx.x * 4 + kc;
        __syncthreads();
        if (t < 64) e[t] = emb[k * 64 + t];
        __syncthreads();
        {
            float acc = 0.0f;
            const float* w = Wd1 + t * 64;
            #pragma unroll
            for (int j = 0; j < 64; ++j) acc = __builtin_fmaf(w[j], e[j], acc);
            h1[t] = selu_f(acc + bd1[t]);
        }
        __syncthreads();
        {
            float acc = 0.0f;
            const float* w = Wd2 + t * 256;
            #pragma unroll 8
            for (int j = 0; j < 256; ++j) acc = __builtin_fmaf(w[j], h1[j], acc);
            h2[t] = selu_f(acc + bd2[t]);
        }
        __syncthreads();
        if (t < 64) {
            float acc = 0.0f;
            const float* w = Wd3 + t * 256;
            #pragma unroll 8
            for (int j = 0; j < 256; ++j) acc = __builtin_fmaf(w[j], h2[j], acc);
            dec_out[k * 64 + t] = acc + bd3[t];
        }
        if (t == 0) {
            float r[8];
            #pragma unroll
            for (int u = 0; u < 8; ++u) r[u] = e[u] * e[u];
            #pragma unroll
            for (int i = 8; i < 64; i += 8) {
                #pragma unroll
                for (int u = 0; u < 8; ++u) { float p = e[i + u] * e[i + u]; r[u] = r[u] + p; }
            }
            en[k] = ((r[0] + r[1]) + (r[2] + r[3])) + ((r[4] + r[5]) + (r[6] + r[7]));
        }
    }
}

// ---------- main kernel ----------
// 256 threads = 4 waves, 64 rows (lane = row). ROUND 1-3 LESSON: 512-thread blocks get pinned
// at a 64-VGPR budget (attributes ignored) -> unavoidable spill; 256-thread blocks proved 128
// VGPRs (round 0). So occupancy must come from LDS, not block size:
//   - h1 is computed in 4 j-chunks of 64 cols into a 17 KB buffer (was a 64 KB full tile);
//     each chunk is immediately folded into 64 persistent per-lane h2 accumulators
//     (wave owns h2 cols [64w,64w+64); j strictly ascending across chunks -> bit-exact).
//   - layer-3 fold stages each wave's 64 h2 cols through one 16 KB buffer (4 serialized
//     folds, c ascending, same ((P0+P1)+(P2+P3))+b3 combine as before -> bit-exact).
// LDS: B0 16 KB (xT -> stage -> cand) + B1 17 KB (h1 chunk -> z park) = 33 KB
// -> 4 blocks/CU x 4 waves = 16 waves/CU = 4 waves/SIMD at <=128 VGPR (2x round-0 occupancy).
__global__ __launch_bounds__(256) __attribute__((amdgpu_waves_per_eu(2)))
void vqvae_main(const float* __restrict__ x,
                const float* __restrict__ b1, const float* __restrict__ b2,
                const float* __restrict__ b3,
                const float* __restrict__ W1T, const float* __restrict__ W2T,
                const float* __restrict__ W3T,
                const float* __restrict__ emb, const float* __restrict__ en,
                const float* __restrict__ dec_out, float* __restrict__ out) {
    __shared__ __align__(16) float B0[4096];   // xT (ph0-1) -> fold stage (ph2b) -> cand (ph5)
    __shared__ __align__(16) float B1[4352];   // h1 chunk, pair layout (ph1-2) -> z park stride 68

    const int t    = threadIdx.x;
    const int wave = t >> 6;      // 0..3
    const int lane = t & 63;
    const size_t rowbase = (size_t)blockIdx.x * 64;

    // opaque zero in a VGPR: keeps uniform loads on the vector pipe (vmcnt, pipelinable)
    int lz;
    asm volatile("v_mov_b32 %0, 0" : "=v"(lz));

    const float* W1Tv = W1T + lz;
    const float* W2Tv = W2T + lz;
    const float* W3Tv = W3T + lz;
    const float* b1v  = b1 + lz;
    const float* b2v  = b2 + lz;
    const float* b3v  = b3 + lz;
    const float* env  = en + lz;
    const float* embv = emb + lz;

    // ---- phase 0: stage x tile transposed into B0: xT[j][r]
    #pragma unroll
    for (int q = 0; q < 4; ++q) {
        int f = t + 256 * q;
        int r = f >> 4, c4 = f & 15;
        float4 v = ldf4(x + (rowbase + r) * 64 + c4 * 4);
        B0[(c4 * 4 + 0) * 64 + r] = v.x;
        B0[(c4 * 4 + 1) * 64 + r] = v.y;
        B0[(c4 * 4 + 2) * 64 + r] = v.z;
        B0[(c4 * 4 + 3) * 64 + r] = v.w;
    }
    __syncthreads();

    // persistent h2 accumulators: wave owns cols [64*wave, 64*wave+64)
    float acc2[64];
    #pragma unroll
    for (int u = 0; u < 64; ++u) acc2[u] = 0.0f;

    // ---- phases 1+2 fused, j-chunked: for each chunk cc, compute h1 cols [64cc,64cc+64)
    // into B1 (pair layout), then accumulate those 64 j's into acc2. j ascending overall.
    for (int cc = 0; cc < 4; ++cc) {
        // phase-1 chunk: wave computes h1 cols cg = 64cc + 16*wave .. +16 (chain: j=0..63 asc)
        {
            const float* wp = W1Tv + cc * 64 + wave * 16;   // row j at wp + j*256
            float4 A[4];
            ld4x4(A, wp);
            float acc[16];
            #pragma unroll
            for (int u = 0; u < 16; ++u) acc[u] = 0.0f;
            #pragma unroll 1
            for (int j = 0; j < 64; ++j) {
                const float* np = wp + (j + 1) * 256;  // j=63 overruns into W3T region (in-ws, unused)
                step16(acc, A, np, B0[j * 64 + lane]);
            }
            float bb[16];
            *(float4*)&bb[0]  = ldf4(b1v + cc * 64 + wave * 16);
            *(float4*)&bb[4]  = ldf4(b1v + cc * 64 + wave * 16 + 4);
            *(float4*)&bb[8]  = ldf4(b1v + cc * 64 + wave * 16 + 8);
            *(float4*)&bb[12] = ldf4(b1v + cc * 64 + wave * 16 + 12);
            float hv[16];
            #pragma unroll
            for (int u = 0; u < 16; ++u) hv[u] = selu_f(acc[u] + bb[u]);
            // pair layout: local j = 16*wave + u; B1[(jl>>1)*128 + 2*lane + (jl&1)]
            #pragma unroll
            for (int up = 0; up < 8; ++up) {
                *(float2*)&B1[(wave * 8 + up) * 128 + (lane << 1)] =
                    make_float2(hv[2 * up], hv[2 * up + 1]);
            }
        }
        __syncthreads();
        // phase-2 chunk: acc2[u] += sum over this chunk's 64 j's (ascending) of W2T[j][64w+u]*h1[j]
        {
            const float* base2 = W2Tv + (cc * 64) * 256 + wave * 64;  // row (64cc+jl), wave cols
            #pragma unroll 1
            for (int jp = 0; jp < 32; ++jp) {
                float2 h01 = *(const float2*)&B1[jp * 128 + (lane << 1)];
                const float* r0 = base2 + jp * 512;       // even j of the pair
                #pragma unroll
                for (int qd = 0; qd < 4; ++qd) {
                    const float* p = r0 + qd * 16;
                    fma16q(acc2 + qd * 16, ldf4(p), ldf4(p + 4), ldf4(p + 8), ldf4(p + 12), h01.x);
                }
                const float* r1 = r0 + 256;               // odd j of the pair
                #pragma unroll
                for (int qd = 0; qd < 4; ++qd) {
                    const float* p = r1 + qd * 16;
                    fma16q(acc2 + qd * 16, ldf4(p), ldf4(p + 4), ldf4(p + 8), ldf4(p + 12), h01.y);
                }
            }
        }
        __syncthreads();   // h1 consumed; next chunk may overwrite (also guards B0 reuse later)
    }

    // h2 = selu(acc2 + b2) in place
    {
        #pragma unroll
        for (int qd = 0; qd < 4; ++qd) {
            float bb[16];
            *(float4*)&bb[0]  = ldf4(b2v + wave * 64 + qd * 16);
            *(float4*)&bb[4]  = ldf4(b2v + wave * 64 + qd * 16 + 4);
            *(float4*)&bb[8]  = ldf4(b2v + wave * 64 + qd * 16 + 8);
            *(float4*)&bb[12] = ldf4(b2v + wave * 64 + qd * 16 + 12);
            #pragma unroll
            for (int i = 0; i < 16; ++i)
                acc2[qd * 16 + i] = selu_f(acc2[qd * 16 + i] + bb[i]);
        }
    }

    // ---- phase 2b: layer-3 fold, staged per col-block g (= wave g's h2 cols), c ascending.
    // z = ((P0+P1)+(P2+P3)) + b3 (identical combine to all passing rounds)
    const int er = wave * 16;
    float s01[16], s23[16];
    for (int g = 0; g < 4; ++g) {
        if (wave == g) {
            #pragma unroll
            for (int u = 0; u < 64; ++u) B0[u * 64 + lane] = acc2[u];
        }
        __syncthreads();   // stage visible to all
        const float* w3p = W3Tv + g * 4096 + er;    // col (64g+c) at w3p + c*64
        float4 F0[4], F1[4];
        ld4x4(F0, w3p); ld4x4(F1, w3p + 64);
        float P[16];
        #pragma unroll
        for (int u = 0; u < 16; ++u) P[u] = 0.0f;
        #pragma unroll 1
        for (int c = 0; c < 64; c += 2) {
            const float* np = w3p + (c + 2) * 64;  // c=62: rows 64..65 overrun into en pad (in-ws)
            step16(P, F0, np,      B0[(c + 0) * 64 + lane]);
            step16(P, F1, np + 64, B0[(c + 1) * 64 + lane]);
        }
        if (g == 0) {
            #pragma unroll
            for (int u = 0; u < 16; ++u) s01[u] = P[u];
        } else if (g == 1) {
            #pragma unroll
            for (int u = 0; u < 16; ++u) s01[u] = s01[u] + P[u];
        } else if (g == 2) {
            #pragma unroll
            for (int u = 0; u < 16; ++u) s23[u] = P[u];
        } else {
            #pragma unroll
            for (int u = 0; u < 16; ++u) s23[u] = s23[u] + P[u];
        }
        __syncthreads();   // folds done before next wave overwrites stage
    }

    // ---- phase 3: z = (s01+s23)+b3; park z in LDS (zs[lane][e], stride 68 -> 2-way free b128)
    {
        float bb[16];
        *(float4*)&bb[0]  = ldf4(b3v + er);
        *(float4*)&bb[4]  = ldf4(b3v + er + 4);
        *(float4*)&bb[8]  = ldf4(b3v + er + 8);
        *(float4*)&bb[12] = ldf4(b3v + er + 12);
        float zv[16];
        #pragma unroll
        for (int u = 0; u < 16; ++u) zv[u] = (s01[u] + s23[u]) + bb[u];
        #pragma unroll
        for (int m = 0; m < 4; ++m)
            *(float4*)&B1[lane * 68 + er + m * 4] =
                make_float4(zv[4 * m], zv[4 * m + 1], zv[4 * m + 2], zv[4 * m + 3]);
    }
    __syncthreads();

    // A = ||z||^2 with numpy pairwise chain (8 strided accumulators, balanced tree), streamed
    float A;
    {
        float r[8];
        {
            float4 v0 = *(const float4*)&B1[lane * 68 + 0];
            float4 v1 = *(const float4*)&B1[lane * 68 + 4];
            r[0] = v0.x * v0.x; r[1] = v0.y * v0.y; r[2] = v0.z * v0.z; r[3] = v0.w * v0.w;
            r[4] = v1.x * v1.x; r[5] = v1.y * v1.y; r[6] = v1.z * v1.z; r[7] = v1.w * v1.w;
        }
        #pragma unroll
        for (int i = 8; i < 64; i += 8) {
            float4 v0 = *(const float4*)&B1[lane * 68 + i];
            float4 v1 = *(const float4*)&B1[lane * 68 + i + 4];
            float p0 = v0.x * v0.x, p1 = v0.y * v0.y, p2 = v0.z * v0.z, p3 = v0.w * v0.w;
            float p4 = v1.x * v1.x, p5 = v1.y * v1.y, p6 = v1.z * v1.z, p7 = v1.w * v1.w;
            r[0] = r[0] + p0; r[1] = r[1] + p1; r[2] = r[2] + p2; r[3] = r[3] + p3;
            r[4] = r[4] + p4; r[5] = r[5] + p5; r[6] = r[6] + p6; r[7] = r[7] + p7;
        }
        A = ((r[0] + r[1]) + (r[2] + r[3])) + ((r[4] + r[5]) + (r[6] + r[7]));
    }

    // ---- phase 4: scores over wave's 256-code slice, 8-code chunks, z quarters re-read from LDS
    float best = 3.4e38f;
    const int k0 = wave * 256;
    int bk = k0;
    const float* embw = embv + (size_t)k0 * 64;
    #pragma unroll 1
    for (int kc = 0; kc < 256; kc += 8) {
        float4 en03 = ldf4(env + k0 + kc);
        float4 en47 = ldf4(env + k0 + kc + 4);
        float d0[8], d1[8], d2[8], d3[8];
        #pragma unroll
        for (int c = 0; c < 8; ++c) { d0[c] = 0.f; d1[c] = 0.f; d2[c] = 0.f; d3[c] = 0.f; }
        #pragma unroll
        for (int q = 0; q < 4; ++q) {
            float4 zq0 = *(const float4*)&B1[lane * 68 + q * 16];
            float4 zq1 = *(const float4*)&B1[lane * 68 + q * 16 + 4];
            float4 zq2 = *(const float4*)&B1[lane * 68 + q * 16 + 8];
            float4 zq3 = *(const float4*)&B1[lane * 68 + q * 16 + 12];
            #pragma unroll
            for (int c = 0; c < 8; ++c) {
                const float* ep = embw + (kc + c) * 64 + q * 16;
                float4 e0 = ldf4(ep), e1 = ldf4(ep + 4), e2 = ldf4(ep + 8), e3 = ldf4(ep + 12);
                d0[c] = __builtin_fmaf(zq0.x, e0.x, d0[c]);
                d1[c] = __builtin_fmaf(zq0.y, e0.y, d1[c]);
                d2[c] = __builtin_fmaf(zq0.z, e0.z, d2[c]);
                d3[c] = __builtin_fmaf(zq0.w, e0.w, d3[c]);
                d0[c] = __builtin_fmaf(zq1.x, e1.x, d0[c]);
                d1[c] = __builtin_fmaf(zq1.y, e1.y, d1[c]);
                d2[c] = __builtin_fmaf(zq1.z, e1.z, d2[c]);
                d3[c] = __builtin_fmaf(zq1.w, e1.w, d3[c]);
                d0[c] = __builtin_fmaf(zq2.x, e2.x, d0[c]);
                d1[c] = __builtin_fmaf(zq2.y, e2.y, d1[c]);
                d2[c] = __builtin_fmaf(zq2.z, e2.z, d2[c]);
                d3[c] = __builtin_fmaf(zq2.w, e2.w, d3[c]);
                d0[c] = __builtin_fmaf(zq3.x, e3.x, d0[c]);
                d1[c] = __builtin_fmaf(zq3.y, e3.y, d1[c]);
                d2[c] = __builtin_fmaf(zq3.z, e3.z, d2[c]);
                d3[c] = __builtin_fmaf(zq3.w, e3.w, d3[c]);
            }
        }
        float enb[8];
        *(float4*)&enb[0] = en03; *(float4*)&enb[4] = en47;
        #pragma unroll
        for (int c = 0; c < 8; ++c) {
            float dot = (d0[c] + d1[c]) + (d2[c] + d3[c]);
            float tt  = __builtin_fmaf(-2.0f, dot, A);
            float s   = tt + enb[c];
            if (s < best) { best = s; bk = k0 + kc + c; }
        }
    }

    // ---- phase 5: cross-wave argmin (ascending wave => first-min); B0 dead -> cand storage
    float* cand_s = B0 + 64;
    int*   cand_k = ((int*)B0) + 320;
    int*   ixp    = (int*)B0;
    cand_s[wave * 64 + lane] = best;
    cand_k[wave * 64 + lane] = bk;
    __syncthreads();
    if (t < 64) {
        float s0 = cand_s[t];
        int   kk = cand_k[t];
        #pragma unroll
        for (int w2 = 1; w2 < 4; ++w2) {
            float sw = cand_s[w2 * 64 + t];
            if (sw < s0) { s0 = sw; kk = cand_k[w2 * 64 + t]; }
        }
        ixp[t] = kk;
        out[(size_t)NROWS * 64 + rowbase + t] = (float)kk;
    }
    __syncthreads();

    // ---- phase 6: recon = dec_out[idx], coalesced f4 store
    #pragma unroll
    for (int q = 0; q < 4; ++q) {
        int f = t + 256 * q;
        int r = f >> 4, c4 = f & 15;
        float4 v = ldf4(dec_out + (size_t)ixp[r] * 64 + c4 * 4);
        *(float4*)(out + (rowbase + r) * 64 + c4 * 4) = v;
    }
}

extern "C" void kernel_launch(void* const* d_in, const int* in_sizes, int n_in,
                              void* d_out, int out_size, void* d_ws, size_t ws_size,
                              hipStream_t stream) {
    const float* x   = (const float*)d_in[0];
    const float* We1 = (const float*)d_in[1];
    const float* be1 = (const float*)d_in[2];
    const float* We2 = (const float*)d_in[3];
    const float* be2 = (const float*)d_in[4];
    const float* We3 = (const float*)d_in[5];
    const float* be3 = (const float*)d_in[6];
    const float* emb = (const float*)d_in[7];
    const float* Wd1 = (const float*)d_in[8];
    const float* bd1 = (const float*)d_in[9];
    const float* Wd2 = (const float*)d_in[10];
    const float* bd2 = (const float*)d_in[11];
    const float* Wd3 = (const float*)d_in[12];
    const float* bd3 = (const float*)d_in[13];
    float* out = (float*)d_out;

    // ws layout (floats): dec_out[65536] | W2T[65536] | W1T[16384] | W3T[16384] | en[1024+pad]
    float* ws      = (float*)d_ws;
    float* dec_out = ws;
    float* W2T     = ws + 65536;
    float* W1T     = ws + 131072;
    float* W3T     = ws + 147456;
    float* en      = ws + 163840;   // en + 1 KB pad absorbs fold prefetch overrun

    prep_transpose<<<384, 256, 0, stream>>>(We1, We2, We3, W1T, W2T, W3T);
    prep_decoder<<<256, 256, 0, stream>>>(emb, Wd1, bd1, Wd2, bd2, Wd3, bd3, dec_out, en);
    vqvae_main<<<NROWS / 64, 256, 0, stream>>>(x, be1, be2, be3, W1T, W2T, W3T, emb, en,
                                               dec_out, out);
}